// Round 3
// baseline (681.436 us; speedup 1.0000x reference)
//
#include <hip/hip_runtime.h>
#include <stdint.h>

typedef __attribute__((ext_vector_type(8))) short short8;
typedef __attribute__((ext_vector_type(4))) float floatx4;

#define SEQQ 256
#define SEQK 256
#define HD   64
#define KSTR 72    // K LDS row stride (bf16): 144 B/row, 16|144 for aligned b128 reads
#define VTSTR 264  // Vt LDS row stride (bf16): 528 B/row
#define PSTR 40    // P scratch row stride (bf16): 80 B/row
#define NW   8     // waves per block

// round-half-up bf16 pack: 2x v_add_u32 + 1x v_perm_b32
__device__ __forceinline__ uint32_t rpack2(float a, float b) {
    uint32_t ua = __builtin_bit_cast(uint32_t, a) + 0x8000u;
    uint32_t ub = __builtin_bit_cast(uint32_t, b) + 0x8000u;
    return __builtin_amdgcn_perm(ub, ua, 0x07060302u);  // [a.hi16 | b.hi16<<16]
}
__device__ __forceinline__ unsigned short f2b(float x) {
    return (unsigned short)((__builtin_bit_cast(uint32_t, x) + 0x8000u) >> 16);
}
__device__ __forceinline__ float b2f(unsigned short b) {
    return __builtin_bit_cast(float, ((uint32_t)b) << 16);
}

// WM fp32 -> bf16 * log2(e) preconvert (exp path then needs no per-element scale)
__global__ __launch_bounds__(256) void wm_convert(const float* __restrict__ wm,
                                                  unsigned short* __restrict__ out) {
    const float LG2E = 1.44269504088896f;
    int i = (blockIdx.x * 256 + threadIdx.x) * 8;
    float4 a = *(const float4*)(wm + i);
    float4 b = *(const float4*)(wm + i + 4);
    uint4 o;
    o.x = rpack2(a.x * LG2E, a.y * LG2E); o.y = rpack2(a.z * LG2E, a.w * LG2E);
    o.z = rpack2(b.x * LG2E, b.y * LG2E); o.w = rpack2(b.z * LG2E, b.w * LG2E);
    *(uint4*)(out + i) = o;
}

__global__ __launch_bounds__(512, 6) void attn_fused(
    const float* __restrict__ Qg, const float* __restrict__ Kg,
    const float* __restrict__ Vg, const int* __restrict__ Lg,
    const unsigned short* __restrict__ WMg, float* __restrict__ Og)
{
    __shared__ __align__(16) unsigned short ldsKV[SEQK * KSTR];      // K tile, then Vt overlays (36864 B)
    __shared__ __align__(16) unsigned short ldsP[NW * 16 * PSTR];    // wave-private P scratch (10240 B)

    const int tid   = threadIdx.x;
    const int lane  = tid & 63;
    const int wave  = tid >> 6;
    const int row16 = lane & 15;
    const int quad  = lane >> 4;

    const int bidx  = blockIdx.x;
    const int batch = bidx >> 1;
    const int qh    = bidx & 1;
    const int q0    = qh * 128 + wave * 16;   // this wave's q-row base

    const float* qptr = Qg + (size_t)batch * SEQQ * HD;
    const float* kptr = Kg + (size_t)batch * SEQK * HD;
    const float* vptr = Vg + (size_t)batch * SEQK * HD;
    const unsigned short* wptr = WMg + (size_t)((batch >> 3) & 63) * SEQQ * SEQK;
    const int L = Lg[batch];

    // ---- stage K -> LDS bf16 [kv][d], float4 loads (8 iters/thread) ----
    #pragma unroll
    for (int it = 0; it < 8; ++it) {
        int pe  = it * 512 + tid;       // 4096 float4's
        int kvr = pe >> 4;
        int pi  = pe & 15;
        const float4 f = *(const float4*)(kptr + kvr * HD + pi * 4);
        uint2 pk; pk.x = rpack2(f.x, f.y); pk.y = rpack2(f.z, f.w);
        *(uint2*)&ldsKV[kvr * KSTR + pi * 4] = pk;
    }

    // ---- Q fragments (A-layout: A[m=lane&15][k=quad*8+j]) ----
    short8 qf0, qf1;
    {
        const float* qr = qptr + (q0 + row16) * HD + quad * 8;
        float4 a = *(const float4*)(qr);
        float4 b = *(const float4*)(qr + 4);
        float4 c = *(const float4*)(qr + 32);
        float4 d = *(const float4*)(qr + 36);
        union { short8 s; uint32_t u[4]; } t0, t1;
        t0.u[0] = rpack2(a.x, a.y); t0.u[1] = rpack2(a.z, a.w);
        t0.u[2] = rpack2(b.x, b.y); t0.u[3] = rpack2(b.z, b.w);
        t1.u[0] = rpack2(c.x, c.y); t1.u[1] = rpack2(c.z, c.w);
        t1.u[2] = rpack2(d.x, d.y); t1.u[3] = rpack2(d.z, d.w);
        qf0 = t0.s; qf1 = t1.s;
    }

    __syncthreads();

    // ---- S = Q K^T ----
    floatx4 acc[16];
    #pragma unroll
    for (int j = 0; j < 16; ++j) acc[j] = (floatx4){0.f, 0.f, 0.f, 0.f};
    #pragma unroll
    for (int j = 0; j < 16; ++j) {
        const unsigned short* kb = &ldsKV[(j * 16 + row16) * KSTR + quad * 8];
        short8 kf0 = *(const short8*)kb;
        short8 kf1 = *(const short8*)(kb + 32);
        acc[j] = __builtin_amdgcn_mfma_f32_16x16x32_bf16(qf0, kf0, acc[j], 0, 0, 0);
        acc[j] = __builtin_amdgcn_mfma_f32_16x16x32_bf16(qf1, kf1, acc[j], 0, 0, 0);
    }

    __syncthreads();   // all waves done reading K; Vt may overlay

    // ---- stage V^T -> LDS bf16 [d][kv]: coalesced row loads + register transpose ----
    #pragma unroll
    for (int it = 0; it < 4; ++it) {
        int u  = it * 512 + tid;        // 2048 units: 2 kv-rows x 4 d each
        int d4 = (u & 15) * 4;
        int kv = (u >> 4) * 2;
        const float4 a = *(const float4*)(vptr + kv * HD + d4);
        const float4 b = *(const float4*)(vptr + (kv + 1) * HD + d4);
        *(uint32_t*)&ldsKV[(d4 + 0) * VTSTR + kv] = rpack2(a.x, b.x);
        *(uint32_t*)&ldsKV[(d4 + 1) * VTSTR + kv] = rpack2(a.y, b.y);
        *(uint32_t*)&ldsKV[(d4 + 2) * VTSTR + kv] = rpack2(a.z, b.z);
        *(uint32_t*)&ldsKV[(d4 + 3) * VTSTR + kv] = rpack2(a.w, b.w);
    }

    // ---- masked softmax in log2 domain (C-layout: q=q0+quad*4+r, kv=16j+row16) ----
    // s' = (S/8 + wm) * log2e ; wm preconverted with log2e folded in.
    float inv[4];
    const float SC = 0.125f * 1.44269504088896f;
    #pragma unroll
    for (int r = 0; r < 4; ++r) {
        const int qrow = q0 + quad * 4 + r;
        const unsigned short* wr = wptr + qrow * SEQK + row16;
        float wv[16];
        #pragma unroll
        for (int j = 0; j < 16; ++j) wv[j] = b2f(wr[16 * j]);
        float mx = -3.0e38f;
        #pragma unroll
        for (int j = 0; j < 16; ++j) {
            float s = acc[j][r] * SC + wv[j];
            s = (16 * j + row16 < L) ? s : -1.0e6f;   // replace (matches reference; L=0 -> uniform)
            acc[j][r] = s;
            mx = fmaxf(mx, s);
        }
        #pragma unroll
        for (int o = 1; o < 16; o <<= 1) mx = fmaxf(mx, __shfl_xor(mx, o, 64));
        float sm = 0.f;
        #pragma unroll
        for (int j = 0; j < 16; ++j) {
            float e = __builtin_amdgcn_exp2f(acc[j][r] - mx);
            acc[j][r] = e;
            sm += e;
        }
        #pragma unroll
        for (int o = 1; o < 16; o <<= 1) sm += __shfl_xor(sm, o, 64);
        inv[r] = __builtin_amdgcn_rcpf(sm);
    }

    __syncthreads();   // Vt fully staged & visible

    // ---- O = P V : per 32-kv chunk, C-layout -> LDS -> A-layout (DS is in-order per wave) ----
    floatx4 oacc[4];
    #pragma unroll
    for (int t = 0; t < 4; ++t) oacc[t] = (floatx4){0.f, 0.f, 0.f, 0.f};
    unsigned short* ps = &ldsP[wave * 16 * PSTR];
    #pragma unroll
    for (int c = 0; c < 8; ++c) {
        #pragma unroll
        for (int r = 0; r < 4; ++r) {
            const int prow = quad * 4 + r;
            ps[prow * PSTR + row16]      = f2b(acc[2 * c    ][r]);   // unnormalized P (<=1)
            ps[prow * PSTR + 16 + row16] = f2b(acc[2 * c + 1][r]);
        }
        __asm__ __volatile__("" ::: "memory");
        __builtin_amdgcn_s_waitcnt(0xC07F);            // lgkmcnt(0): wave-synchronous round trip
        short8 pf = *(const short8*)&ps[row16 * PSTR + quad * 8];
        #pragma unroll
        for (int t = 0; t < 4; ++t) {
            short8 vf = *(const short8*)&ldsKV[(t * 16 + row16) * VTSTR + c * 32 + quad * 8];
            oacc[t] = __builtin_amdgcn_mfma_f32_16x16x32_bf16(pf, vf, oacc[t], 0, 0, 0);
        }
        __asm__ __volatile__("" ::: "memory");
    }

    // ---- store O, folding 1/rowsum here (16 muls instead of 64 on P) ----
    float* op = Og + (size_t)batch * SEQQ * HD;
    #pragma unroll
    for (int t = 0; t < 4; ++t) {
        #pragma unroll
        for (int r = 0; r < 4; ++r) {
            op[(q0 + quad * 4 + r) * HD + t * 16 + row16] = oacc[t][r] * inv[r];
        }
    }
}

extern "C" void kernel_launch(void* const* d_in, const int* in_sizes, int n_in,
                              void* d_out, int out_size, void* d_ws, size_t ws_size,
                              hipStream_t stream) {
    const float* Qg = (const float*)d_in[0];
    const float* Kg = (const float*)d_in[1];
    const float* Vg = (const float*)d_in[2];
    const int*   Lg = (const int*)d_in[3];
    const float* Wm = (const float*)d_in[4];
    float* Og = (float*)d_out;

    const int nbatch = in_sizes[3];          // 2048
    const int wm_elems = in_sizes[4];        // 64*256*256

    unsigned short* wmb = (unsigned short*)d_ws;
    hipLaunchKernelGGL(wm_convert, dim3(wm_elems / 2048), dim3(256), 0, stream, Wm, wmb);
    hipLaunchKernelGGL(attn_fused, dim3(nbatch * 2), dim3(512), 0, stream,
                       Qg, Kg, Vg, Lg, wmb, Og);
}